// Round 9
// baseline (43.357 us; speedup 1.0000x reference)
//
#include <hip/hip_runtime.h>
#include <math.h>

#define N_G   4096
#define IMW   96
#define TILE  8             // 8x8 px tiles
#define TILES_X 12
#define NTILE (TILES_X*TILES_X)   // 144
#define TCAP  512           // per-tile list capacity
#define NTHR  512           // render block threads (8 waves)
#define NSEG  8             // threads per pixel (depth segments)
#define FXI   (1.0f/96.0f)
#define NEARP 0.3f
#define EPSV  1e-8f
#define LOG2E 1.4426950408889634f
#define CULL_K 26.0f        // drop alpha < opa * 2^-26 within tile

typedef unsigned long long ull;

// ---------------- K1: preprocess once per gaussian + bin into tile lists ----
// un4 slot0: {mu, mv, iaP, ibP}  slot1: {idP, opa_eff, cr, cg}  slot2: {cb,-,-,-}
// tlist[tile*TCAP + slot] = (rr_bits<<32)|gi  (order normalized by K2 sort)
__global__ __launch_bounds__(256) void bin_k(
    const float* __restrict__ pos, const float* __restrict__ rgb,
    const float* __restrict__ opa, const float* __restrict__ quat,
    const float* __restrict__ scale, const float* __restrict__ rot,
    const float* __restrict__ tran,
    float4* __restrict__ un4, int* __restrict__ tcnt, ull* __restrict__ tlist)
{
    int i = blockIdx.x * blockDim.x + threadIdx.x;
    if (i >= N_G) return;

    float R00=rot[0],R01=rot[1],R02=rot[2];
    float R10=rot[3],R11=rot[4],R12=rot[5];
    float R20=rot[6],R21=rot[7],R22=rot[8];
    float t0=tran[0], t1=tran[1], t2=tran[2];

    float p0 = pos[i*3+0], p1 = pos[i*3+1], p2 = pos[i*3+2];
    float x = R00*p0 + R01*p1 + R02*p2 + t0;
    float y = R10*p0 + R11*p1 + R12*p2 + t1;
    float z = R20*p0 + R21*p1 + R22*p2 + t2;
    float rr = sqrtf(x*x + y*y + z*z);
    float invz = 1.0f / z;
    float mu = x * invz, mv = y * invz;

    float J02 = -x*invz*invz, J12 = -y*invz*invz;
    float JW00 = invz*R00 + J02*R20;
    float JW01 = invz*R01 + J02*R21;
    float JW02 = invz*R02 + J02*R22;
    float JW10 = invz*R10 + J12*R20;
    float JW11 = invz*R11 + J12*R21;
    float JW12 = invz*R12 + J12*R22;

    float qw = quat[i*4+0], qx = quat[i*4+1], qy = quat[i*4+2], qz = quat[i*4+3];
    float qn = sqrtf(qw*qw+qx*qx+qy*qy+qz*qz) + 1e-12f;
    float qi = 1.0f/qn;
    qw*=qi; qx*=qi; qy*=qi; qz*=qi;
    float Q00=1.f-2.f*(qy*qy+qz*qz), Q01=2.f*(qx*qy-qw*qz), Q02=2.f*(qx*qz+qw*qy);
    float Q10=2.f*(qx*qy+qw*qz), Q11=1.f-2.f*(qx*qx+qz*qz), Q12=2.f*(qy*qz-qw*qx);
    float Q20=2.f*(qx*qz-qw*qy), Q21=2.f*(qy*qz+qw*qx), Q22=1.f-2.f*(qx*qx+qy*qy);

    float sa=fabsf(scale[i*3+0])+1e-4f;
    float sb=fabsf(scale[i*3+1])+1e-4f;
    float sc=fabsf(scale[i*3+2])+1e-4f;
    float A00=Q00*sa,A01=Q01*sb,A02=Q02*sc;
    float A10=Q10*sa,A11=Q11*sb,A12=Q12*sc;
    float A20=Q20*sa,A21=Q21*sb,A22=Q22*sc;
    float C00=A00*A00+A01*A01+A02*A02;
    float C01=A00*A10+A01*A11+A02*A12;
    float C02=A00*A20+A01*A21+A02*A22;
    float C11=A10*A10+A11*A11+A12*A12;
    float C12=A10*A20+A11*A21+A12*A22;
    float C22=A20*A20+A21*A21+A22*A22;
    float M00=JW00*C00+JW01*C01+JW02*C02;
    float M01=JW00*C01+JW01*C11+JW02*C12;
    float M02=JW00*C02+JW01*C12+JW02*C22;
    float M10=JW10*C00+JW11*C01+JW12*C02;
    float M11=JW10*C01+JW11*C11+JW12*C12;
    float M12=JW10*C02+JW11*C12+JW12*C22;
    float a  = M00*JW00+M01*JW01+M02*JW02 + EPSV;
    float d  = M10*JW10+M11*JW11+M12*JW12 + EPSV;
    float bb = 0.5f*((M00*JW10+M01*JW11+M02*JW12)+(M10*JW00+M11*JW01+M12*JW02));
    float invdet = 1.0f/(a*d - bb*bb);
    float iaP = -0.5f*d*invdet*LOG2E;
    float ibP =  bb*invdet*LOG2E;
    float idP = -0.5f*a*invdet*LOG2E;

    float sig_o = 1.0f/(1.0f+__expf(-opa[i]));
    float opa_eff = (z > NEARP) ? sig_o : 0.0f;
    float c0 = 1.0f/(1.0f+__expf(-rgb[i*3+0]));
    float c1 = 1.0f/(1.0f+__expf(-rgb[i*3+1]));
    float c2 = 1.0f/(1.0f+__expf(-rgb[i*3+2]));

    un4[i*3+0] = make_float4(mu, mv, iaP, ibP);
    un4[i*3+1] = make_float4(idP, opa_eff, c0, c1);
    un4[i*3+2] = make_float4(c2, 0.0f, 0.0f, 0.0f);

    // exact conservative cull circle (identical to rounds 7/8)
    float q00 = -iaP, q01 = -0.5f*ibP, q11 = -idP;
    float df = q00 - q11;
    float lam = 0.5f*((q00 + q11) - sqrtf(df*df + 4.0f*q01*q01));
    lam = fmaxf(lam, 1e-20f);
    float r2 = (CULL_K + log2f(opa_eff)) / lam;   // -inf when opa_eff==0
    if (!(r2 > 0.0f)) return;

    float r = sqrtf(r2);
    // tile bbox (conservative by one tile each side; exact test filters)
    float pxlo = (mu - r)*96.0f + 47.5f, pxhi = (mu + r)*96.0f + 47.5f;
    float pylo = (mv - r)*96.0f + 47.5f, pyhi = (mv + r)*96.0f + 47.5f;
    int txmin = max(0, (int)floorf((pxlo - 7.0f)*0.125f));
    int txmax = min(TILES_X-1, (int)floorf(pxhi*0.125f) + 1);
    int tymin = max(0, (int)floorf((pylo - 7.0f)*0.125f));
    int tymax = min(TILES_X-1, (int)floorf(pyhi*0.125f) + 1);

    ull key = ((ull)__float_as_uint(rr) << 32) | (unsigned int)i;
    for (int ty = tymin; ty <= tymax; ty++) {
        float v0 = ((float)(ty*TILE) + 0.5f - 48.0f) * FXI;
        float v1 = v0 + (TILE-1) * FXI;
        float cv = fminf(fmaxf(mv, v0), v1);
        float ddy = mv - cv;
        for (int tx = txmin; tx <= txmax; tx++) {
            float u0 = ((float)(tx*TILE) + 0.5f - 48.0f) * FXI;
            float u1 = u0 + (TILE-1) * FXI;
            float cu = fminf(fmaxf(mu, u0), u1);
            float ddx = mu - cu;
            if (ddx*ddx + ddy*ddy <= r2) {
                int tile = ty*TILES_X + tx;
                int slot = atomicAdd(&tcnt[tile], 1);
                if (slot < TCAP) tlist[tile*TCAP + slot] = key;
            }
        }
    }
}

// ---------------- K2: per-tile sort + composite ------------------------------
__global__ __launch_bounds__(NTHR, 1) void render_k(
    const float4* __restrict__ un4, const int* __restrict__ tcnt,
    const ull* __restrict__ tlist, float* __restrict__ out)
{
    __shared__ ull skey[TCAP];
    __shared__ float4 g0[TCAP], g1[TCAP], g2[TCAP];
    __shared__ float4 pix[NTHR];

    const int t = threadIdx.x;
    const int tile = blockIdx.x;
    const int tx = tile % TILES_X, ty = tile / TILES_X;

    int cnt = tcnt[tile];
    if (cnt > TCAP) cnt = TCAP;

    if (t < cnt) skey[t] = tlist[tile*TCAP + t];
    __syncthreads();

    // in-place rank sort by (rr_bits, gi) -- order-append independent
    ull v = 0; int r = -1;
    if (t < cnt) {
        v = skey[t];
        r = 0;
        for (int j = 0; j < cnt; j++) r += (skey[j] < v) ? 1 : 0;
    }
    __syncthreads();
    if (r >= 0) skey[r] = v;
    __syncthreads();

    // gather sorted survivor params
    if (t < cnt) {
        int gi = (int)(skey[t] & 0xffffffffu);
        g0[t] = un4[gi*3+0];
        g1[t] = un4[gi*3+1];
        g2[t] = un4[gi*3+2];
    }
    __syncthreads();

    // 8-way depth-segmented composite
    const int seg = t >> 6, pid = t & 63;
    const int px = tx*TILE + (pid & (TILE-1));
    const int py = ty*TILE + (pid / TILE);
    const float pu = ((float)px + 0.5f - 48.0f) * FXI;
    const float pv = ((float)py + 0.5f - 48.0f) * FXI;

    const int per = (cnt + NSEG - 1) / NSEG;
    const int sA = min(seg * per, cnt);
    const int sB = min(sA + per, cnt);

    float T = 1.0f, cr = 0.0f, cg = 0.0f, cb = 0.0f;
    #pragma unroll 2
    for (int s = sA; s < sB; s++) {
        float4 a0 = g0[s];
        float4 a1 = g1[s];
        float4 a2 = g2[s];
        float dx = pu - a0.x;
        float dy = pv - a0.y;
        float pw = dx*(a0.z*dx + a0.w*dy) + a1.x*dy*dy;   // log2-scaled power
        float al = fminf(a1.y * __builtin_amdgcn_exp2f(pw), 0.99f);
        float w = T * al;
        cr += w * a1.z;
        cg += w * a1.w;
        cb += w * a2.x;
        T *= (1.0f - al);
    }
    pix[t] = make_float4(cr, cg, cb, T);
    __syncthreads();

    // merge 8 depth segments front-to-back, store
    if (t < TILE*TILE) {
        float orr = 0.0f, og = 0.0f, ob = 0.0f, T2 = 1.0f;
        #pragma unroll
        for (int s = 0; s < NSEG; s++) {
            float4 P = pix[s*64 + t];
            orr += T2 * P.x;
            og  += T2 * P.y;
            ob  += T2 * P.z;
            T2  *= P.w;
        }
        int pixel = py * IMW + px;
        out[pixel*3+0] = orr;
        out[pixel*3+1] = og;
        out[pixel*3+2] = ob;
    }
}

extern "C" void kernel_launch(void* const* d_in, const int* in_sizes, int n_in,
                              void* d_out, int out_size, void* d_ws, size_t ws_size,
                              hipStream_t stream) {
    const float* pos   = (const float*)d_in[0];
    const float* rgb   = (const float*)d_in[1];
    const float* opa   = (const float*)d_in[2];
    const float* quat  = (const float*)d_in[3];
    const float* scale = (const float*)d_in[4];
    const float* rot   = (const float*)d_in[5];
    const float* tran  = (const float*)d_in[6];
    float* out = (float*)d_out;

    char* ws = (char*)d_ws;
    float4* un4  = (float4*)ws;                          // 4096*3*16 = 196608 B
    ull*   tlist = (ull*)(ws + 196608);                  // 144*512*8 = 589824 B
    int*   tcnt  = (int*)(ws + 196608 + 589824);         // 144*4 B

    hipMemsetAsync(tcnt, 0, NTILE*sizeof(int), stream);
    bin_k<<<N_G/256, 256, 0, stream>>>(pos, rgb, opa, quat, scale, rot, tran,
                                       un4, tcnt, tlist);
    render_k<<<NTILE, NTHR, 0, stream>>>(un4, tcnt, tlist, out);
}

// Round 10
// 18.492 us; speedup vs baseline: 2.3447x; 2.3447x over previous
//
#include <hip/hip_runtime.h>
#include <math.h>

#define N_G   4096
#define IMW   96
#define TILE  4             // 4x4 px tiles
#define TILES_X 24
#define NTILE (TILES_X*TILES_X)   // 576 blocks
#define NTHR  256           // 4 waves per block
#define NW    (NTHR/64)     // 4 waves
#define NST   (N_G/NTHR)    // 16 cull stages
#define NSEG  16            // threads per pixel (depth segments)
#define BCAP  1536          // max bound-phase survivors per tile
#define CAP   512           // max exact survivors per tile
#define FXI   (1.0f/96.0f)
#define NEARP 0.3f
#define EPSV  1e-8f
#define LOG2E 1.4426950408889634f
#define LN2   0.6931471805599453f
#define CULL_K 26.0f        // drop alpha < opa * 2^-26 within tile

typedef unsigned long long ull;

// Single kernel, one block per 4x4 tile.
// A: cheap conservative bound (Frobenius-norm, no JW) over all 4096 -> compact
// B: exact params + exact cull on bound-survivors -> compact (order = gi asc)
// C: in-place rank sort by (depth_key, slot)   D: 16-way segmented composite
// E: merge + store.
__global__ __launch_bounds__(NTHR, 2) void splat_k(
    const float* __restrict__ pos, const float* __restrict__ rgb,
    const float* __restrict__ opa, const float* __restrict__ quat,
    const float* __restrict__ scale, const float* __restrict__ rot,
    const float* __restrict__ tran, float* __restrict__ out)
{
    __shared__ unsigned int bl[BCAP];
    __shared__ ull skey[CAP];
    __shared__ float4 g0[CAP], g1[CAP], g2[CAP];
    __shared__ float4 pix[NTHR];
    __shared__ int wsA[NST][NW];
    __shared__ int wsB[NW];

    const int t = threadIdx.x;
    const int tile = blockIdx.x;
    const int tx = tile % TILES_X, ty = tile / TILES_X;
    const float u0 = ((float)(tx*TILE) + 0.5f - 48.0f) * FXI;
    const float u1 = u0 + (TILE-1) * FXI;
    const float v0 = ((float)(ty*TILE) + 0.5f - 48.0f) * FXI;
    const float v1 = v0 + (TILE-1) * FXI;
    const int wid = t >> 6, lane = t & 63;

    float R00=rot[0],R01=rot[1],R02=rot[2];
    float R10=rot[3],R11=rot[4],R12=rot[5];
    float R20=rot[6],R21=rot[7],R22=rot[8];
    float t0=tran[0], t1=tran[1], t2=tran[2];

    // ---- Phase A: cheap conservative bound cull (one barrier per stage) ----
    int bcnt = 0;
    #pragma unroll
    for (int st = 0; st < NST; st++) {
        int gi = st*NTHR + t;
        float p0=pos[gi*3+0], p1=pos[gi*3+1], p2=pos[gi*3+2];
        float o = opa[gi];
        float s0=scale[gi*3+0], s1=scale[gi*3+1], s2=scale[gi*3+2];

        float x = R00*p0 + R01*p1 + R02*p2 + t0;
        float y = R10*p0 + R11*p1 + R12*p2 + t1;
        float z = R20*p0 + R21*p1 + R22*p2 + t2;
        float invz = 1.0f/z;
        float mu = x*invz, mv = y*invz;

        // ||J*W||_F^2 == ||J||_F^2 (W orthonormal): 2/z^2 + (x^2+y^2)/z^4
        float inz2 = invz*invz;
        float fn = 2.0f*inz2 + (x*x + y*y)*inz2*inz2;
        float smax = fmaxf(fmaxf(fabsf(s0), fabsf(s1)), fabsf(s2)) + 1e-4f;
        float lmax = fn*smax*smax + EPSV;      // >= lam_max(cov2d)
        float amp = CULL_K + 1.0f + fminf(0.0f, o*LOG2E);
        float r2b = amp * lmax * (2.0f*LN2) * 1.02f;

        float cu = fminf(fmaxf(mu, u0), u1);
        float cv = fminf(fmaxf(mv, v0), v1);
        float ddx = mu - cu, ddy = mv - cv;
        bool flag = (z > NEARP) && (amp > 0.0f) && (ddx*ddx + ddy*ddy <= r2b);

        ull m = __ballot(flag);
        if (lane == 0) wsA[st][wid] = __popcll(m);
        __syncthreads();
        int base = bcnt, tot = 0;
        #pragma unroll
        for (int w = 0; w < NW; w++) { int c = wsA[st][w]; if (w < wid) base += c; tot += c; }
        if (flag) {
            int p = base + __popcll(m & ((1ull << lane) - 1ull));
            if (p < BCAP) bl[p] = (unsigned int)gi;
        }
        bcnt += tot;
        // no second barrier: wsA slots are per-stage; bl reads happen after
        // the next stage's barrier (and a final one below)
    }
    if (bcnt > BCAP) bcnt = BCAP;
    __syncthreads();

    // ---- Phase B: exact params + exact cull for bound-survivors ----
    int cnt = 0;
    for (int s0i = 0; s0i < bcnt; s0i += NTHR) {
        int s = s0i + t;
        bool flag = false;
        float4 o0, o1, o2; float rr = 0.0f;
        if (s < bcnt) {
            int gi = bl[s];
            float p0=pos[gi*3+0], p1=pos[gi*3+1], p2=pos[gi*3+2];
            float x = R00*p0 + R01*p1 + R02*p2 + t0;
            float y = R10*p0 + R11*p1 + R12*p2 + t1;
            float z = R20*p0 + R21*p1 + R22*p2 + t2;
            rr = sqrtf(x*x + y*y + z*z);
            float invz = 1.0f/z;
            float mu = x*invz, mv = y*invz;

            float J02 = -x*invz*invz, J12 = -y*invz*invz;
            float JW00 = invz*R00 + J02*R20;
            float JW01 = invz*R01 + J02*R21;
            float JW02 = invz*R02 + J02*R22;
            float JW10 = invz*R10 + J12*R20;
            float JW11 = invz*R11 + J12*R21;
            float JW12 = invz*R12 + J12*R22;

            float qw=quat[gi*4+0], qx=quat[gi*4+1], qy=quat[gi*4+2], qz=quat[gi*4+3];
            float qn = sqrtf(qw*qw+qx*qx+qy*qy+qz*qz) + 1e-12f;
            float qi = 1.0f/qn;
            qw*=qi; qx*=qi; qy*=qi; qz*=qi;
            float Q00=1.f-2.f*(qy*qy+qz*qz), Q01=2.f*(qx*qy-qw*qz), Q02=2.f*(qx*qz+qw*qy);
            float Q10=2.f*(qx*qy+qw*qz), Q11=1.f-2.f*(qx*qx+qz*qz), Q12=2.f*(qy*qz-qw*qx);
            float Q20=2.f*(qx*qz-qw*qy), Q21=2.f*(qy*qz+qw*qx), Q22=1.f-2.f*(qx*qx+qy*qy);

            float sa=fabsf(scale[gi*3+0])+1e-4f;
            float sb=fabsf(scale[gi*3+1])+1e-4f;
            float sc=fabsf(scale[gi*3+2])+1e-4f;
            float A00=Q00*sa,A01=Q01*sb,A02=Q02*sc;
            float A10=Q10*sa,A11=Q11*sb,A12=Q12*sc;
            float A20=Q20*sa,A21=Q21*sb,A22=Q22*sc;
            float C00=A00*A00+A01*A01+A02*A02;
            float C01=A00*A10+A01*A11+A02*A12;
            float C02=A00*A20+A01*A21+A02*A22;
            float C11=A10*A10+A11*A11+A12*A12;
            float C12=A10*A20+A11*A21+A12*A22;
            float C22=A20*A20+A21*A21+A22*A22;
            float M00=JW00*C00+JW01*C01+JW02*C02;
            float M01=JW00*C01+JW01*C11+JW02*C12;
            float M02=JW00*C02+JW01*C12+JW02*C22;
            float M10=JW10*C00+JW11*C01+JW12*C02;
            float M11=JW10*C01+JW11*C11+JW12*C12;
            float M12=JW10*C02+JW11*C12+JW12*C22;
            float a  = M00*JW00+M01*JW01+M02*JW02 + EPSV;
            float d  = M10*JW10+M11*JW11+M12*JW12 + EPSV;
            float bb = 0.5f*((M00*JW10+M01*JW11+M02*JW12)+(M10*JW00+M11*JW01+M12*JW02));
            float invdet = 1.0f/(a*d - bb*bb);
            float iaP = -0.5f*d*invdet*LOG2E;
            float ibP =  bb*invdet*LOG2E;
            float idP = -0.5f*a*invdet*LOG2E;

            float sig_o = 1.0f/(1.0f+__expf(-opa[gi]));
            float opa_eff = (z > NEARP) ? sig_o : 0.0f;

            float q00 = -iaP, q01 = -0.5f*ibP, q11 = -idP;
            float df = q00 - q11;
            float lam = 0.5f*((q00 + q11) - sqrtf(df*df + 4.0f*q01*q01));
            lam = fmaxf(lam, 1e-20f);
            float r2 = (CULL_K + log2f(opa_eff)) / lam;

            float cu = fminf(fmaxf(mu, u0), u1);
            float cv = fminf(fmaxf(mv, v0), v1);
            float ddx = mu - cu, ddy = mv - cv;
            flag = (ddx*ddx + ddy*ddy) <= r2;

            if (flag) {
                float c0 = 1.0f/(1.0f+__expf(-rgb[gi*3+0]));
                float c1 = 1.0f/(1.0f+__expf(-rgb[gi*3+1]));
                float c2 = 1.0f/(1.0f+__expf(-rgb[gi*3+2]));
                o0 = make_float4(mu, mv, iaP, ibP);
                o1 = make_float4(idP, opa_eff, c0, c1);
                o2 = make_float4(c2, 0.0f, 0.0f, 0.0f);
            }
        }
        ull m = __ballot(flag);
        if (lane == 0) wsB[wid] = __popcll(m);
        __syncthreads();
        int base = cnt, tot = 0;
        #pragma unroll
        for (int w = 0; w < NW; w++) { int c = wsB[w]; if (w < wid) base += c; tot += c; }
        if (flag) {
            int p = base + __popcll(m & ((1ull << lane) - 1ull));
            if (p < CAP) {
                g0[p] = o0; g1[p] = o1; g2[p] = o2;
                // slot order == bl order == gi ascending -> stable tie-break
                skey[p] = ((ull)__float_as_uint(rr) << 32) | (unsigned int)p;
            }
        }
        cnt += tot;
        __syncthreads();
    }
    if (cnt > CAP) cnt = CAP;

    // ---- Phase C: in-place rank sort by (key_bits, slot) ----
    ull v = 0; int r = -1;
    if (t < cnt) {
        v = skey[t];
        r = 0;
        for (int j = 0; j < cnt; j++) r += (skey[j] < v) ? 1 : 0;
    }
    __syncthreads();
    if (r >= 0) skey[r] = v;
    __syncthreads();

    // ---- Phase D: 16-way depth-segmented composite ----
    const int seg = t >> 4, pid = t & 15;
    const int px = tx*TILE + (pid & (TILE-1));
    const int py = ty*TILE + (pid / TILE);
    const float pu = ((float)px + 0.5f - 48.0f) * FXI;
    const float pv = ((float)py + 0.5f - 48.0f) * FXI;

    const int per = (cnt + NSEG - 1) / NSEG;
    const int sA = min(seg * per, cnt);
    const int sB = min(sA + per, cnt);

    float T = 1.0f, cr = 0.0f, cg = 0.0f, cb = 0.0f;
    for (int s = sA; s < sB; s++) {
        int slot = (int)(skey[s] & 0xffffffffu);
        float4 a0 = g0[slot];
        float4 a1 = g1[slot];
        float4 a2 = g2[slot];
        float dx = pu - a0.x;
        float dy = pv - a0.y;
        float pw = dx*(a0.z*dx + a0.w*dy) + a1.x*dy*dy;   // log2-scaled power
        float al = fminf(a1.y * __builtin_amdgcn_exp2f(pw), 0.99f);
        float w = T * al;
        cr += w * a1.z;
        cg += w * a1.w;
        cb += w * a2.x;
        T *= (1.0f - al);
    }
    pix[t] = make_float4(cr, cg, cb, T);
    __syncthreads();

    // ---- Phase E: merge 16 depth segments front-to-back, store ----
    if (t < TILE*TILE) {
        float orr = 0.0f, og = 0.0f, ob = 0.0f, T2 = 1.0f;
        #pragma unroll
        for (int s = 0; s < NSEG; s++) {
            float4 P = pix[s*16 + t];
            orr += T2 * P.x;
            og  += T2 * P.y;
            ob  += T2 * P.z;
            T2  *= P.w;
        }
        int pixel = py * IMW + px;
        out[pixel*3+0] = orr;
        out[pixel*3+1] = og;
        out[pixel*3+2] = ob;
    }
}

extern "C" void kernel_launch(void* const* d_in, const int* in_sizes, int n_in,
                              void* d_out, int out_size, void* d_ws, size_t ws_size,
                              hipStream_t stream) {
    const float* pos   = (const float*)d_in[0];
    const float* rgb   = (const float*)d_in[1];
    const float* opa   = (const float*)d_in[2];
    const float* quat  = (const float*)d_in[3];
    const float* scale = (const float*)d_in[4];
    const float* rot   = (const float*)d_in[5];
    const float* tran  = (const float*)d_in[6];
    float* out = (float*)d_out;

    splat_k<<<NTILE, NTHR, 0, stream>>>(pos, rgb, opa, quat, scale, rot, tran, out);
}

// Round 11
// 14.944 us; speedup vs baseline: 2.9014x; 1.2374x over previous
//
#include <hip/hip_runtime.h>
#include <math.h>

#define N_G   4096
#define IMW   96
#define TILE  6             // 6x6 px tiles
#define TILES_X 16
#define NTILE (TILES_X*TILES_X)   // 256 blocks == 256 CUs
#define NTHR  1024          // 16 waves per block
#define NW    (NTHR/64)     // 16 waves
#define NST   (N_G/NTHR)    // 4 cull stages
#define NPX   (TILE*TILE)   // 36 pixels per tile
#define NSEG  16            // depth segments per pixel
#define BCAP  2048          // max bound-phase survivors per tile
#define CAP   512           // max exact survivors per tile
#define FXI   (1.0f/96.0f)
#define NEARP 0.3f
#define EPSV  1e-8f
#define LOG2E 1.4426950408889634f
#define LN2   0.6931471805599453f
#define CULL_K 26.0f        // drop alpha < opa * 2^-26 within tile

typedef unsigned long long ull;

// Single kernel, one block per 6x6 tile (256 blocks = 1/CU, 16 waves each).
// A: prefetched cheap conservative bound over all 4096 -> compact (4 stages)
// B: exact params + exact cull on bound-survivors -> compact (order = gi asc)
// C: in-place rank sort by (depth_key, slot)   D: 16-way segmented composite
// E: merge + store.
__global__ __launch_bounds__(NTHR, 1) void splat_k(
    const float* __restrict__ pos, const float* __restrict__ rgb,
    const float* __restrict__ opa, const float* __restrict__ quat,
    const float* __restrict__ scale, const float* __restrict__ rot,
    const float* __restrict__ tran, float* __restrict__ out)
{
    __shared__ unsigned int bl[BCAP];
    __shared__ ull skey[CAP];
    __shared__ float4 g0[CAP], g1[CAP], g2[CAP];
    __shared__ float4 pix[NSEG*NPX];
    __shared__ int wsA[NST][NW];
    __shared__ int wsB[NW];

    const int t = threadIdx.x;
    const int tile = blockIdx.x;
    const int tx = tile % TILES_X, ty = tile / TILES_X;
    const float u0 = ((float)(tx*TILE) + 0.5f - 48.0f) * FXI;
    const float u1 = u0 + (TILE-1) * FXI;
    const float v0 = ((float)(ty*TILE) + 0.5f - 48.0f) * FXI;
    const float v1 = v0 + (TILE-1) * FXI;
    const int wid = t >> 6, lane = t & 63;

    float R00=rot[0],R01=rot[1],R02=rot[2];
    float R10=rot[3],R11=rot[4],R12=rot[5];
    float R20=rot[6],R21=rot[7],R22=rot[8];
    float t0=tran[0], t1=tran[1], t2=tran[2];

    // ---- Phase A prefetch: issue all 4 stages' loads up front ----
    float pp0[NST], pp1[NST], pp2[NST], po[NST], ps0[NST], ps1[NST], ps2[NST];
    #pragma unroll
    for (int st = 0; st < NST; st++) {
        int gi = st*NTHR + t;
        pp0[st]=pos[gi*3+0]; pp1[st]=pos[gi*3+1]; pp2[st]=pos[gi*3+2];
        po[st]=opa[gi];
        ps0[st]=scale[gi*3+0]; ps1[st]=scale[gi*3+1]; ps2[st]=scale[gi*3+2];
    }

    // ---- Phase A: cheap conservative bound cull (one barrier per stage) ----
    int bcnt = 0;
    #pragma unroll
    for (int st = 0; st < NST; st++) {
        int gi = st*NTHR + t;
        float x = R00*pp0[st] + R01*pp1[st] + R02*pp2[st] + t0;
        float y = R10*pp0[st] + R11*pp1[st] + R12*pp2[st] + t1;
        float z = R20*pp0[st] + R21*pp1[st] + R22*pp2[st] + t2;
        float invz = 1.0f/z;
        float mu = x*invz, mv = y*invz;

        // ||J*W||_F^2 == ||J||_F^2 (W orthonormal): 2/z^2 + (x^2+y^2)/z^4
        float inz2 = invz*invz;
        float fn = 2.0f*inz2 + (x*x + y*y)*inz2*inz2;
        float smax = fmaxf(fmaxf(fabsf(ps0[st]), fabsf(ps1[st])), fabsf(ps2[st])) + 1e-4f;
        float lmax = fn*smax*smax + EPSV;      // >= lam_max(cov2d)
        float amp = CULL_K + 1.0f + fminf(0.0f, po[st]*LOG2E);
        float r2b = amp * lmax * (2.0f*LN2) * 1.02f;

        float cu = fminf(fmaxf(mu, u0), u1);
        float cv = fminf(fmaxf(mv, v0), v1);
        float ddx = mu - cu, ddy = mv - cv;
        bool flag = (z > NEARP) && (amp > 0.0f) && (ddx*ddx + ddy*ddy <= r2b);

        ull m = __ballot(flag);
        if (lane == 0) wsA[st][wid] = __popcll(m);
        __syncthreads();
        int base = bcnt, tot = 0;
        #pragma unroll
        for (int w = 0; w < NW; w++) { int c = wsA[st][w]; if (w < wid) base += c; tot += c; }
        if (flag) {
            int p = base + __popcll(m & ((1ull << lane) - 1ull));
            if (p < BCAP) bl[p] = (unsigned int)gi;
        }
        bcnt += tot;
        // per-stage wsA slots -> no trailing barrier needed inside the loop
    }
    if (bcnt > BCAP) bcnt = BCAP;
    __syncthreads();   // bl visible to Phase B

    // ---- Phase B: exact params + exact cull for bound-survivors ----
    int cnt = 0;
    for (int s0i = 0; s0i < bcnt; s0i += NTHR) {
        int s = s0i + t;
        bool flag = false;
        float4 o0, o1, o2; float rr = 0.0f;
        if (s < bcnt) {
            int gi = bl[s];
            float p0=pos[gi*3+0], p1=pos[gi*3+1], p2=pos[gi*3+2];
            float x = R00*p0 + R01*p1 + R02*p2 + t0;
            float y = R10*p0 + R11*p1 + R12*p2 + t1;
            float z = R20*p0 + R21*p1 + R22*p2 + t2;
            rr = sqrtf(x*x + y*y + z*z);
            float invz = 1.0f/z;
            float mu = x*invz, mv = y*invz;

            float J02 = -x*invz*invz, J12 = -y*invz*invz;
            float JW00 = invz*R00 + J02*R20;
            float JW01 = invz*R01 + J02*R21;
            float JW02 = invz*R02 + J02*R22;
            float JW10 = invz*R10 + J12*R20;
            float JW11 = invz*R11 + J12*R21;
            float JW12 = invz*R12 + J12*R22;

            float qw=quat[gi*4+0], qx=quat[gi*4+1], qy=quat[gi*4+2], qz=quat[gi*4+3];
            float qn = sqrtf(qw*qw+qx*qx+qy*qy+qz*qz) + 1e-12f;
            float qi = 1.0f/qn;
            qw*=qi; qx*=qi; qy*=qi; qz*=qi;
            float Q00=1.f-2.f*(qy*qy+qz*qz), Q01=2.f*(qx*qy-qw*qz), Q02=2.f*(qx*qz+qw*qy);
            float Q10=2.f*(qx*qy+qw*qz), Q11=1.f-2.f*(qx*qx+qz*qz), Q12=2.f*(qy*qz-qw*qx);
            float Q20=2.f*(qx*qz-qw*qy), Q21=2.f*(qy*qz+qw*qx), Q22=1.f-2.f*(qx*qx+qy*qy);

            float sa=fabsf(scale[gi*3+0])+1e-4f;
            float sb=fabsf(scale[gi*3+1])+1e-4f;
            float sc=fabsf(scale[gi*3+2])+1e-4f;
            float A00=Q00*sa,A01=Q01*sb,A02=Q02*sc;
            float A10=Q10*sa,A11=Q11*sb,A12=Q12*sc;
            float A20=Q20*sa,A21=Q21*sb,A22=Q22*sc;
            float C00=A00*A00+A01*A01+A02*A02;
            float C01=A00*A10+A01*A11+A02*A12;
            float C02=A00*A20+A01*A21+A02*A22;
            float C11=A10*A10+A11*A11+A12*A12;
            float C12=A10*A20+A11*A21+A12*A22;
            float C22=A20*A20+A21*A21+A22*A22;
            float M00=JW00*C00+JW01*C01+JW02*C02;
            float M01=JW00*C01+JW01*C11+JW02*C12;
            float M02=JW00*C02+JW01*C12+JW02*C22;
            float M10=JW10*C00+JW11*C01+JW12*C02;
            float M11=JW10*C01+JW11*C11+JW12*C12;
            float M12=JW10*C02+JW11*C12+JW12*C22;
            float a  = M00*JW00+M01*JW01+M02*JW02 + EPSV;
            float d  = M10*JW10+M11*JW11+M12*JW12 + EPSV;
            float bb = 0.5f*((M00*JW10+M01*JW11+M02*JW12)+(M10*JW00+M11*JW01+M12*JW02));
            float invdet = 1.0f/(a*d - bb*bb);
            float iaP = -0.5f*d*invdet*LOG2E;
            float ibP =  bb*invdet*LOG2E;
            float idP = -0.5f*a*invdet*LOG2E;

            float sig_o = 1.0f/(1.0f+__expf(-opa[gi]));
            float opa_eff = (z > NEARP) ? sig_o : 0.0f;

            float q00 = -iaP, q01 = -0.5f*ibP, q11 = -idP;
            float df = q00 - q11;
            float lam = 0.5f*((q00 + q11) - sqrtf(df*df + 4.0f*q01*q01));
            lam = fmaxf(lam, 1e-20f);
            float r2 = (CULL_K + log2f(opa_eff)) / lam;

            float cu = fminf(fmaxf(mu, u0), u1);
            float cv = fminf(fmaxf(mv, v0), v1);
            float ddx = mu - cu, ddy = mv - cv;
            flag = (ddx*ddx + ddy*ddy) <= r2;

            if (flag) {
                float c0 = 1.0f/(1.0f+__expf(-rgb[gi*3+0]));
                float c1 = 1.0f/(1.0f+__expf(-rgb[gi*3+1]));
                float c2 = 1.0f/(1.0f+__expf(-rgb[gi*3+2]));
                o0 = make_float4(mu, mv, iaP, ibP);
                o1 = make_float4(idP, opa_eff, c0, c1);
                o2 = make_float4(c2, 0.0f, 0.0f, 0.0f);
            }
        }
        ull m = __ballot(flag);
        if (lane == 0) wsB[wid] = __popcll(m);
        __syncthreads();
        int base = cnt, tot = 0;
        #pragma unroll
        for (int w = 0; w < NW; w++) { int c = wsB[w]; if (w < wid) base += c; tot += c; }
        if (flag) {
            int p = base + __popcll(m & ((1ull << lane) - 1ull));
            if (p < CAP) {
                g0[p] = o0; g1[p] = o1; g2[p] = o2;
                // slot order == bl order == gi ascending -> stable tie-break
                skey[p] = ((ull)__float_as_uint(rr) << 32) | (unsigned int)p;
            }
        }
        cnt += tot;
        __syncthreads();
    }
    if (cnt > CAP) cnt = CAP;

    // ---- Phase C: in-place rank sort by (key_bits, slot) ----
    ull v = 0; int r = -1;
    if (t < cnt) {
        v = skey[t];
        r = 0;
        for (int j = 0; j < cnt; j++) r += (skey[j] < v) ? 1 : 0;
    }
    __syncthreads();
    if (r >= 0) skey[r] = v;
    __syncthreads();

    // ---- Phase D: 16-way depth-segmented composite (576 active threads) ----
    if (t < NSEG*NPX) {
        const int seg = t / NPX, pid = t % NPX;
        const int px = tx*TILE + (pid % TILE);
        const int py = ty*TILE + (pid / TILE);
        const float pu = ((float)px + 0.5f - 48.0f) * FXI;
        const float pv = ((float)py + 0.5f - 48.0f) * FXI;

        const int per = (cnt + NSEG - 1) / NSEG;
        const int sA = min(seg * per, cnt);
        const int sB = min(sA + per, cnt);

        float T = 1.0f, cr = 0.0f, cg = 0.0f, cb = 0.0f;
        for (int s = sA; s < sB; s++) {
            int slot = (int)(skey[s] & 0xffffffffu);
            float4 a0 = g0[slot];
            float4 a1 = g1[slot];
            float4 a2 = g2[slot];
            float dx = pu - a0.x;
            float dy = pv - a0.y;
            float pw = dx*(a0.z*dx + a0.w*dy) + a1.x*dy*dy;   // log2-scaled
            float al = fminf(a1.y * __builtin_amdgcn_exp2f(pw), 0.99f);
            float w = T * al;
            cr += w * a1.z;
            cg += w * a1.w;
            cb += w * a2.x;
            T *= (1.0f - al);
        }
        pix[t] = make_float4(cr, cg, cb, T);
    }
    __syncthreads();

    // ---- Phase E: merge 16 depth segments front-to-back, store ----
    if (t < NPX) {
        float orr = 0.0f, og = 0.0f, ob = 0.0f, T2 = 1.0f;
        #pragma unroll
        for (int s = 0; s < NSEG; s++) {
            float4 P = pix[s*NPX + t];
            orr += T2 * P.x;
            og  += T2 * P.y;
            ob  += T2 * P.z;
            T2  *= P.w;
        }
        int px = tx*TILE + (t % TILE);
        int py = ty*TILE + (t / TILE);
        int pixel = py * IMW + px;
        out[pixel*3+0] = orr;
        out[pixel*3+1] = og;
        out[pixel*3+2] = ob;
    }
}

extern "C" void kernel_launch(void* const* d_in, const int* in_sizes, int n_in,
                              void* d_out, int out_size, void* d_ws, size_t ws_size,
                              hipStream_t stream) {
    const float* pos   = (const float*)d_in[0];
    const float* rgb   = (const float*)d_in[1];
    const float* opa   = (const float*)d_in[2];
    const float* quat  = (const float*)d_in[3];
    const float* scale = (const float*)d_in[4];
    const float* rot   = (const float*)d_in[5];
    const float* tran  = (const float*)d_in[6];
    float* out = (float*)d_out;

    splat_k<<<NTILE, NTHR, 0, stream>>>(pos, rgb, opa, quat, scale, rot, tran, out);
}